// Round 1
// baseline (4532.336 us; speedup 1.0000x reference)
//
#include <hip/hip_runtime.h>
#include <cstddef>

#define NN 50000
#define NREL 3
#define NE 250000
#define NP 100000
#define FIN 128
#define HD 256
#define SLOPE 0.2f

// ---------------- f32 tiled GEMM: C[M,N] = A[M,K] @ B[K,N] (row-major) ----
__global__ __launch_bounds__(256) void gemm_f32(
    const float* __restrict__ A, const float* __restrict__ B,
    float* __restrict__ C, int M, int N, int K)
{
  __shared__ float As[32][68];   // [k][m], padded
  __shared__ float Bs[32][64];   // [k][n]
  const int tx = threadIdx.x & 15;
  const int ty = threadIdx.x >> 4;
  const int row0 = blockIdx.x * 64;
  const int col0 = blockIdx.y * 64;
  float acc[4][4] = {};
  for (int k0 = 0; k0 < K; k0 += 32) {
    const int t  = threadIdx.x;
    const int kk = (t & 7) * 4;
    const int rr = t >> 3;
#pragma unroll
    for (int i = 0; i < 2; ++i) {
      int r = rr + i * 32;
      int gr = row0 + r; if (gr > M - 1) gr = M - 1;   // clamp (stores guarded)
      const float4 v = *(const float4*)&A[(size_t)gr * K + k0 + kk];
      As[kk + 0][r] = v.x; As[kk + 1][r] = v.y;
      As[kk + 2][r] = v.z; As[kk + 3][r] = v.w;
    }
    const int nn = (t & 15) * 4;
    const int kr = t >> 4;
#pragma unroll
    for (int i = 0; i < 2; ++i) {
      int k = kr + i * 16;
      *(float4*)&Bs[k][nn] = *(const float4*)&B[(size_t)(k0 + k) * N + col0 + nn];
    }
    __syncthreads();
#pragma unroll
    for (int k = 0; k < 32; ++k) {
      const float4 av = *(const float4*)&As[k][ty * 4];
      const float4 bv = *(const float4*)&Bs[k][tx * 4];
      const float a_[4] = {av.x, av.y, av.z, av.w};
      const float b_[4] = {bv.x, bv.y, bv.z, bv.w};
#pragma unroll
      for (int i = 0; i < 4; ++i)
#pragma unroll
        for (int j = 0; j < 4; ++j)
          acc[i][j] = fmaf(a_[i], b_[j], acc[i][j]);
    }
    __syncthreads();
  }
#pragma unroll
  for (int i = 0; i < 4; ++i) {
    int row = row0 + ty * 4 + i;
    if (row < M) {
      float4 st = {acc[i][0], acc[i][1], acc[i][2], acc[i][3]};
      *(float4*)&C[(size_t)row * N + col0 + tx * 4] = st;
    }
  }
}

// ------------- per-row dual dot: el[i]=feat[i,:]·al, er[i]=feat[i,:]·ar ----
__global__ __launch_bounds__(256) void rowdot2(
    const float* __restrict__ feat, const float* __restrict__ al,
    const float* __restrict__ ar, float* __restrict__ el,
    float* __restrict__ er, int M, int H)
{
  const int wid  = (blockIdx.x * blockDim.x + threadIdx.x) >> 6;
  const int lane = threadIdx.x & 63;
  if (wid >= M) return;
  float sl = 0.f, sr = 0.f;
  for (int c = lane; c < H; c += 64) {
    float f = feat[(size_t)wid * H + c];
    sl += f * al[c];
    sr += f * ar[c];
  }
#pragma unroll
  for (int off = 32; off > 0; off >>= 1) {
    sl += __shfl_down(sl, off);
    sr += __shfl_down(sr, off);
  }
  if (lane == 0) { el[wid] = sl; er[wid] = sr; }
}

__device__ __forceinline__ unsigned enc_f(float f) {
  unsigned b = __float_as_uint(f);
  return (b & 0x80000000u) ? ~b : (b | 0x80000000u);
}
__device__ __forceinline__ float dec_f(unsigned u) {
  return (u & 0x80000000u) ? __uint_as_float(u & 0x7FFFFFFFu)
                           : __uint_as_float(~u);
}

// ------------- per-edge score + segment max (encoded uint atomicMax) -------
__global__ __launch_bounds__(256) void edge_score(
    const int* __restrict__ src, const int* __restrict__ dst,
    const float* __restrict__ el, const float* __restrict__ er,
    float* __restrict__ scores, unsigned* __restrict__ menc, int E)
{
  int e = blockIdx.x * blockDim.x + threadIdx.x;
  if (e >= E) return;
  float sc = el[src[e]] + er[dst[e]];
  sc = sc > 0.f ? sc : SLOPE * sc;
  scores[e] = sc;
  atomicMax(&menc[dst[e]], enc_f(sc));
}

// ------------- a = exp(score - m[dst]); denom += a -------------------------
__global__ __launch_bounds__(256) void edge_exp(
    const int* __restrict__ dst, float* __restrict__ scores,
    const unsigned* __restrict__ menc, float* __restrict__ denom, int E)
{
  int e = blockIdx.x * blockDim.x + threadIdx.x;
  if (e >= E) return;
  int d = dst[e];
  float a = expf(scores[e] - dec_f(menc[d]));
  scores[e] = a;
  atomicAdd(&denom[d], a);
}

// ------------- out[dst] += feat[src] * a ----------------------------------
__global__ __launch_bounds__(256) void edge_scatter(
    const int* __restrict__ src, const int* __restrict__ dst,
    const float* __restrict__ a, const float* __restrict__ feat,
    float* __restrict__ outb, int E, int H)
{
  const int per = H >> 2;
  int tid = blockIdx.x * blockDim.x + threadIdx.x;
  if (tid >= E * per) return;
  int e  = tid / per;
  int cg = tid - e * per;
  int s = src[e], d = dst[e];
  float av = a[e];
  const float4 f = *(const float4*)&feat[(size_t)s * H + cg * 4];
  float* o = &outb[(size_t)d * H + cg * 4];
  atomicAdd(o + 0, f.x * av);
  atomicAdd(o + 1, f.y * av);
  atomicAdd(o + 2, f.z * av);
  atomicAdd(o + 3, f.w * av);
}

// ------------- acc += outb/max(denom,1e-9) + bias -------------------------
__global__ __launch_bounds__(256) void finalize_accum(
    const float* __restrict__ outb, const float* __restrict__ denom,
    const float* __restrict__ bias, float* __restrict__ acc, int M, int H)
{
  const int per = H >> 2;
  int idx = blockIdx.x * blockDim.x + threadIdx.x;
  if (idx >= M * per) return;
  int i  = idx / per;
  int cg = idx - i * per;
  float inv = 1.f / fmaxf(denom[i], 1e-9f);
  float4 v  = ((const float4*)outb)[idx];
  float4 bv = *(const float4*)&bias[cg * 4];
  float4 a  = ((float4*)acc)[idx];
  a.x += v.x * inv + bv.x;
  a.y += v.y * inv + bv.y;
  a.z += v.z * inv + bv.z;
  a.w += v.w * inv + bv.w;
  ((float4*)acc)[idx] = a;
}

// ------------- p *= s; optional relu (in place, float4) -------------------
__global__ __launch_bounds__(256) void scale_relu(
    float* __restrict__ p, float s, int do_relu, int n4)
{
  int idx = blockIdx.x * blockDim.x + threadIdx.x;
  if (idx >= n4) return;
  float4 v = ((float4*)p)[idx];
  v.x *= s; v.y *= s; v.z *= s; v.w *= s;
  if (do_relu) {
    v.x = fmaxf(v.x, 0.f); v.y = fmaxf(v.y, 0.f);
    v.z = fmaxf(v.z, 0.f); v.w = fmaxf(v.w, 0.f);
  }
  ((float4*)p)[idx] = v;
}

// ------------- per-node predictor dots: dotl/dotr (H=128) -----------------
__global__ __launch_bounds__(256) void node_dots(
    const float* __restrict__ hn, const float* __restrict__ Wlin,
    float* __restrict__ dotl, float* __restrict__ dotr, int M)
{
  const int wid  = (blockIdx.x * blockDim.x + threadIdx.x) >> 6;
  const int lane = threadIdx.x & 63;
  if (wid >= M) return;
  float f1 = fmaxf(hn[(size_t)wid * FIN + lane], 0.f);
  float f2 = fmaxf(hn[(size_t)wid * FIN + lane + 64], 0.f);
  float dl = f1 * Wlin[lane] + f2 * Wlin[lane + 64];
  float dr = f1 * Wlin[FIN + lane] + f2 * Wlin[FIN + lane + 64];
#pragma unroll
  for (int off = 32; off > 0; off >>= 1) {
    dl += __shfl_down(dl, off);
    dr += __shfl_down(dr, off);
  }
  if (lane == 0) { dotl[wid] = dl; dotr[wid] = dr; }
}

// ------------- pair logits -------------------------------------------------
__global__ __launch_bounds__(256) void pair_out(
    const int* __restrict__ edges, const int* __restrict__ n_pairs,
    const float* __restrict__ dotl, const float* __restrict__ dotr,
    const float* __restrict__ blin, float* __restrict__ out)
{
  const int TOT = NREL * NE + NP;
  int p = blockIdx.x * blockDim.x + threadIdx.x;
  if (p >= TOT) return;
  int s, d;
  if (p < NREL * NE) {
    int r = p / NE;
    int e = p - r * NE;
    const int* base = edges + (size_t)r * 2 * NE;
    s = base[e];
    d = base[NE + e];
  } else {
    int q = p - NREL * NE;
    s = n_pairs[2 * q];
    d = n_pairs[2 * q + 1];
  }
  float logit = dotl[s] + dotr[d] + blin[0];
  out[p] = 1.f / (1.f + expf(-logit));
}

extern "C" void kernel_launch(void* const* d_in, const int* in_sizes, int n_in,
                              void* d_out, int out_size, void* d_ws, size_t ws_size,
                              hipStream_t stream) {
  const float* x      = (const float*)d_in[0];
  const int*   edges  = (const int*)d_in[1];
  const int*   npairs = (const int*)d_in[2];
  const float* W1     = (const float*)d_in[3];
  const float* al1    = (const float*)d_in[4];
  const float* ar1    = (const float*)d_in[5];
  const float* b1     = (const float*)d_in[6];
  const float* W2     = (const float*)d_in[7];
  const float* al2    = (const float*)d_in[8];
  const float* ar2    = (const float*)d_in[9];
  const float* b2     = (const float*)d_in[10];
  const float* Wlin   = (const float*)d_in[11];
  const float* blin   = (const float*)d_in[12];
  float* out = (float*)d_out;

  const size_t SZ_NH = (size_t)NN * HD * sizeof(float);   // 51.2 MB
  const size_t SZ_NF = (size_t)NN * FIN * sizeof(float);  // 25.6 MB
  const size_t SZ_N  = (size_t)NN * sizeof(float);
  const size_t SZ_E  = (size_t)NE * sizeof(float);

  char* w = (char*)d_ws;
  float*    hsum   = (float*)(w);                          // N x 256 accum -> h
  float*    feat   = (float*)(w + SZ_NH);                  // N x 256
  float*    outb   = (float*)(w + 2 * SZ_NH);              // N x 256
  float*    hn     = (float*)(w + 3 * SZ_NH);              // N x 128 accum
  char*     w2     = w + 3 * SZ_NH + SZ_NF;
  float*    el     = (float*)(w2);
  float*    er     = (float*)(w2 + SZ_N);
  unsigned* menc   = (unsigned*)(w2 + 2 * SZ_N);
  float*    denom  = (float*)(w2 + 3 * SZ_N);
  float*    scores = (float*)(w2 + 4 * SZ_N);
  float*    dotl   = (float*)(w2 + 4 * SZ_N + SZ_E);
  float*    dotr   = (float*)(w2 + 5 * SZ_N + SZ_E);

  const int B = 256;

  // ---------------- layer 1: x(128) -> h1(256), mean+relu -----------------
  hipMemsetAsync(hsum, 0, SZ_NH, stream);
  for (int r = 0; r < NREL; ++r) {
    dim3 g1((NN + 63) / 64, HD / 64);
    gemm_f32<<<g1, B, 0, stream>>>(x, W1 + (size_t)r * FIN * HD, feat, NN, HD, FIN);
    rowdot2<<<(NN + 3) / 4, B, 0, stream>>>(feat, al1 + (size_t)r * HD,
                                            ar1 + (size_t)r * HD, el, er, NN, HD);
    hipMemsetAsync(menc, 0, SZ_N, stream);
    hipMemsetAsync(denom, 0, SZ_N, stream);
    hipMemsetAsync(outb, 0, SZ_NH, stream);
    const int* srcp = edges + (size_t)r * 2 * NE;
    const int* dstp = srcp + NE;
    edge_score<<<(NE + B - 1) / B, B, 0, stream>>>(srcp, dstp, el, er, scores, menc, NE);
    edge_exp<<<(NE + B - 1) / B, B, 0, stream>>>(dstp, scores, menc, denom, NE);
    edge_scatter<<<((size_t)NE * (HD / 4) + B - 1) / B, B, 0, stream>>>(
        srcp, dstp, scores, feat, outb, NE, HD);
    finalize_accum<<<(NN * (HD / 4) + B - 1) / B, B, 0, stream>>>(
        outb, denom, b1 + (size_t)r * HD, hsum, NN, HD);
  }
  scale_relu<<<(NN * (HD / 4) + B - 1) / B, B, 0, stream>>>(
      hsum, 1.f / 3.f, 1, NN * (HD / 4));

  // ---------------- layer 2: h(256) -> h2(128), mean ----------------------
  hipMemsetAsync(hn, 0, SZ_NF, stream);
  for (int r = 0; r < NREL; ++r) {
    dim3 g2((NN + 63) / 64, FIN / 64);
    gemm_f32<<<g2, B, 0, stream>>>(hsum, W2 + (size_t)r * HD * FIN, feat, NN, FIN, HD);
    rowdot2<<<(NN + 3) / 4, B, 0, stream>>>(feat, al2 + (size_t)r * FIN,
                                            ar2 + (size_t)r * FIN, el, er, NN, FIN);
    hipMemsetAsync(menc, 0, SZ_N, stream);
    hipMemsetAsync(denom, 0, SZ_N, stream);
    hipMemsetAsync(outb, 0, SZ_NF, stream);
    const int* srcp = edges + (size_t)r * 2 * NE;
    const int* dstp = srcp + NE;
    edge_score<<<(NE + B - 1) / B, B, 0, stream>>>(srcp, dstp, el, er, scores, menc, NE);
    edge_exp<<<(NE + B - 1) / B, B, 0, stream>>>(dstp, scores, menc, denom, NE);
    edge_scatter<<<((size_t)NE * (FIN / 4) + B - 1) / B, B, 0, stream>>>(
        srcp, dstp, scores, feat, outb, NE, FIN);
    finalize_accum<<<(NN * (FIN / 4) + B - 1) / B, B, 0, stream>>>(
        outb, denom, b2 + (size_t)r * FIN, hn, NN, FIN);
  }
  scale_relu<<<(NN * (FIN / 4) + B - 1) / B, B, 0, stream>>>(
      hn, 1.f / 3.f, 0, NN * (FIN / 4));

  // ---------------- pair predictor ----------------------------------------
  node_dots<<<(NN + 3) / 4, B, 0, stream>>>(hn, Wlin, dotl, dotr, NN);
  const int TOT = NREL * NE + NP;
  pair_out<<<(TOT + B - 1) / B, B, 0, stream>>>(edges, npairs, dotl, dotr, blin, out);
}

// Round 3
// 838.393 us; speedup vs baseline: 5.4060x; 5.4060x over previous
//
#include <hip/hip_runtime.h>
#include <cstddef>

#define NN 50000
#define NREL 3
#define NE 250000
#define NP 100000
#define FIN 128
#define HD 256
#define SLOPE 0.2f

// ---------------- f32 tiled GEMM: C[M,N] = A[M,K] @ B[K,N] (row-major) ----
__global__ __launch_bounds__(256) void gemm_f32(
    const float* __restrict__ A, const float* __restrict__ B,
    float* __restrict__ C, int M, int N, int K)
{
  __shared__ float As[32][68];   // [k][m], padded
  __shared__ float Bs[32][64];   // [k][n]
  const int tx = threadIdx.x & 15;
  const int ty = threadIdx.x >> 4;
  const int row0 = blockIdx.x * 64;
  const int col0 = blockIdx.y * 64;
  float acc[4][4] = {};
  for (int k0 = 0; k0 < K; k0 += 32) {
    const int t  = threadIdx.x;
    const int kk = (t & 7) * 4;
    const int rr = t >> 3;
#pragma unroll
    for (int i = 0; i < 2; ++i) {
      int r = rr + i * 32;
      int gr = row0 + r; if (gr > M - 1) gr = M - 1;   // clamp (stores guarded)
      const float4 v = *(const float4*)&A[(size_t)gr * K + k0 + kk];
      As[kk + 0][r] = v.x; As[kk + 1][r] = v.y;
      As[kk + 2][r] = v.z; As[kk + 3][r] = v.w;
    }
    const int nn = (t & 15) * 4;
    const int kr = t >> 4;
#pragma unroll
    for (int i = 0; i < 2; ++i) {
      int k = kr + i * 16;
      *(float4*)&Bs[k][nn] = *(const float4*)&B[(size_t)(k0 + k) * N + col0 + nn];
    }
    __syncthreads();
#pragma unroll
    for (int k = 0; k < 32; ++k) {
      const float4 av = *(const float4*)&As[k][ty * 4];
      const float4 bv = *(const float4*)&Bs[k][tx * 4];
      const float a_[4] = {av.x, av.y, av.z, av.w};
      const float b_[4] = {bv.x, bv.y, bv.z, bv.w};
#pragma unroll
      for (int i = 0; i < 4; ++i)
#pragma unroll
        for (int j = 0; j < 4; ++j)
          acc[i][j] = fmaf(a_[i], b_[j], acc[i][j]);
    }
    __syncthreads();
  }
#pragma unroll
  for (int i = 0; i < 4; ++i) {
    int row = row0 + ty * 4 + i;
    if (row < M) {
      float4 st = {acc[i][0], acc[i][1], acc[i][2], acc[i][3]};
      *(float4*)&C[(size_t)row * N + col0 + tx * 4] = st;
    }
  }
}

// ------------- per-row dual dot: el[i]=feat[i,:]·al, er[i]=feat[i,:]·ar ----
__global__ __launch_bounds__(256) void rowdot2(
    const float* __restrict__ feat, const float* __restrict__ al,
    const float* __restrict__ ar, float* __restrict__ el,
    float* __restrict__ er, int M, int H)
{
  const int wid  = (blockIdx.x * blockDim.x + threadIdx.x) >> 6;
  const int lane = threadIdx.x & 63;
  if (wid >= M) return;
  float sl = 0.f, sr = 0.f;
  for (int c = lane; c < H; c += 64) {
    float f = feat[(size_t)wid * H + c];
    sl += f * al[c];
    sr += f * ar[c];
  }
#pragma unroll
  for (int off = 32; off > 0; off >>= 1) {
    sl += __shfl_down(sl, off);
    sr += __shfl_down(sr, off);
  }
  if (lane == 0) { el[wid] = sl; er[wid] = sr; }
}

// ------------- CSR build: degree count ------------------------------------
__global__ __launch_bounds__(256) void count_deg(
    const int* __restrict__ edges, int* __restrict__ deg)
{
  int tid = blockIdx.x * blockDim.x + threadIdx.x;
  if (tid >= NREL * NE) return;
  int r = tid / NE;
  int e = tid - r * NE;
  int d = edges[(size_t)r * 2 * NE + NE + e];
  atomicAdd(&deg[r * NN + d], 1);
}

// ------------- CSR build: per-relation exclusive scan ---------------------
// block b handles relation b; segmented ownership -> ONE block scan total.
__global__ __launch_bounds__(1024) void scan_deg(
    const int* __restrict__ deg, int* __restrict__ row_ptr)
{
  __shared__ int lds[1024];
  const int r = blockIdx.x;
  const int t = threadIdx.x;
  const int SEG = (NN + 1023) / 1024;       // 49
  const int base = r * NN;
  const int lo = t * SEG;
  const int hi = (lo + SEG < NN) ? lo + SEG : NN;
  int sum = 0;
  for (int i = lo; i < hi; ++i) sum += deg[base + i];
  lds[t] = sum;
  __syncthreads();
  // Hillis-Steele inclusive scan
  for (int off = 1; off < 1024; off <<= 1) {
    int add = (t >= off) ? lds[t - off] : 0;
    __syncthreads();
    lds[t] += add;
    __syncthreads();
  }
  int excl = lds[t] - sum;
  int run = r * NE + excl;
  for (int i = lo; i < hi; ++i) {
    row_ptr[base + i] = run;
    run += deg[base + i];
  }
  if (r == NREL - 1 && t == 1023) row_ptr[NREL * NN] = NREL * NE;
}

// ------------- CSR build: fill src lists ----------------------------------
__global__ __launch_bounds__(256) void fill_csr(
    const int* __restrict__ edges, const int* __restrict__ row_ptr,
    int* __restrict__ cursor, int* __restrict__ csr_src)
{
  int tid = blockIdx.x * blockDim.x + threadIdx.x;
  if (tid >= NREL * NE) return;
  int r = tid / NE;
  int e = tid - r * NE;
  const int* base = edges + (size_t)r * 2 * NE;
  int s = base[e];
  int d = base[NE + e];
  int pos = atomicAdd(&cursor[r * NN + d], 1);
  csr_src[row_ptr[r * NN + d] + pos] = s;
}

// ------------- fused GAT aggregate: one wave per dst node -----------------
// softmax over in-edges + weighted gather-sum + normalize + bias, and
// accumulate across relations (first==1 overwrites).
// NOTE: row_ptr values are ABSOLUTE into csr_src (they include the r*NE
// offset), so csr_src must be passed UNoffset.
template<int H>
__global__ __launch_bounds__(256) void gat_aggregate(
    const int* __restrict__ row_ptr, const int* __restrict__ csr_src,
    const float* __restrict__ el, const float* __restrict__ er,
    const float* __restrict__ feat, const float* __restrict__ bias,
    float* __restrict__ acc, int first)
{
  constexpr int V = H / 64;                    // floats per lane
  typedef float vec_t __attribute__((ext_vector_type(V)));
  const int lane = threadIdx.x & 63;
  const int node = blockIdx.x * 4 + (threadIdx.x >> 6);
  if (node >= NN) return;
  const int beg = row_ptr[node];
  const int end = row_ptr[node + 1];
  const float eri = er[node];

  // pass 1: segment max
  float m = -3.4e38f;
  for (int e = beg + lane; e < end; e += 64) {
    float s = el[csr_src[e]] + eri;
    s = s > 0.f ? s : SLOPE * s;
    m = fmaxf(m, s);
  }
#pragma unroll
  for (int off = 32; off > 0; off >>= 1) m = fmaxf(m, __shfl_xor(m, off));

  // pass 2: exp, denom, weighted gather
  float denom = 0.f;
  vec_t facc = (vec_t)0.f;
  for (int chunk = beg; chunk < end; chunk += 64) {
    int e = chunk + lane;
    float a = 0.f;
    int sidx = 0;
    if (e < end) {
      sidx = csr_src[e];
      float s = el[sidx] + eri;
      s = s > 0.f ? s : SLOPE * s;
      a = __expf(s - m);
    }
    const int cnt = (end - chunk < 64) ? end - chunk : 64;
    for (int j = 0; j < cnt; ++j) {
      float aj = __shfl(a, j);
      int   sj = __shfl(sidx, j);
      denom += aj;
      const vec_t f = *(const vec_t*)&feat[(size_t)sj * H + lane * V];
      facc += f * aj;
    }
  }
  const float inv = 1.f / fmaxf(denom, 1e-9f);
  const vec_t bv = *(const vec_t*)&bias[lane * V];
  vec_t res = facc * inv + bv;
  float* dst = &acc[(size_t)node * H + lane * V];
  if (!first) res += *(const vec_t*)dst;
  *(vec_t*)dst = res;
}

// ------------- p *= s; optional relu (in place, float4) -------------------
__global__ __launch_bounds__(256) void scale_relu(
    float* __restrict__ p, float s, int do_relu, int n4)
{
  int idx = blockIdx.x * blockDim.x + threadIdx.x;
  if (idx >= n4) return;
  float4 v = ((float4*)p)[idx];
  v.x *= s; v.y *= s; v.z *= s; v.w *= s;
  if (do_relu) {
    v.x = fmaxf(v.x, 0.f); v.y = fmaxf(v.y, 0.f);
    v.z = fmaxf(v.z, 0.f); v.w = fmaxf(v.w, 0.f);
  }
  ((float4*)p)[idx] = v;
}

// ------------- per-node predictor dots: dotl/dotr (H=128) -----------------
__global__ __launch_bounds__(256) void node_dots(
    const float* __restrict__ hn, const float* __restrict__ Wlin,
    float* __restrict__ dotl, float* __restrict__ dotr, int M)
{
  const int wid  = (blockIdx.x * blockDim.x + threadIdx.x) >> 6;
  const int lane = threadIdx.x & 63;
  if (wid >= M) return;
  float f1 = fmaxf(hn[(size_t)wid * FIN + lane], 0.f);
  float f2 = fmaxf(hn[(size_t)wid * FIN + lane + 64], 0.f);
  float dl = f1 * Wlin[lane] + f2 * Wlin[lane + 64];
  float dr = f1 * Wlin[FIN + lane] + f2 * Wlin[FIN + lane + 64];
#pragma unroll
  for (int off = 32; off > 0; off >>= 1) {
    dl += __shfl_down(dl, off);
    dr += __shfl_down(dr, off);
  }
  if (lane == 0) { dotl[wid] = dl; dotr[wid] = dr; }
}

// ------------- pair logits -------------------------------------------------
__global__ __launch_bounds__(256) void pair_out(
    const int* __restrict__ edges, const int* __restrict__ n_pairs,
    const float* __restrict__ dotl, const float* __restrict__ dotr,
    const float* __restrict__ blin, float* __restrict__ out)
{
  const int TOT = NREL * NE + NP;
  int p = blockIdx.x * blockDim.x + threadIdx.x;
  if (p >= TOT) return;
  int s, d;
  if (p < NREL * NE) {
    int r = p / NE;
    int e = p - r * NE;
    const int* base = edges + (size_t)r * 2 * NE;
    s = base[e];
    d = base[NE + e];
  } else {
    int q = p - NREL * NE;
    s = n_pairs[2 * q];
    d = n_pairs[2 * q + 1];
  }
  float logit = dotl[s] + dotr[d] + blin[0];
  out[p] = 1.f / (1.f + expf(-logit));
}

extern "C" void kernel_launch(void* const* d_in, const int* in_sizes, int n_in,
                              void* d_out, int out_size, void* d_ws, size_t ws_size,
                              hipStream_t stream) {
  const float* x      = (const float*)d_in[0];
  const int*   edges  = (const int*)d_in[1];
  const int*   npairs = (const int*)d_in[2];
  const float* W1     = (const float*)d_in[3];
  const float* al1    = (const float*)d_in[4];
  const float* ar1    = (const float*)d_in[5];
  const float* b1     = (const float*)d_in[6];
  const float* W2     = (const float*)d_in[7];
  const float* al2    = (const float*)d_in[8];
  const float* ar2    = (const float*)d_in[9];
  const float* b2     = (const float*)d_in[10];
  const float* Wlin   = (const float*)d_in[11];
  const float* blin   = (const float*)d_in[12];
  float* out = (float*)d_out;

  const size_t SZ_NH = (size_t)NN * HD * sizeof(float);   // 51.2 MB
  const size_t SZ_NF = (size_t)NN * FIN * sizeof(float);  // 25.6 MB
  const size_t SZ_N  = (size_t)NN * sizeof(float);        // 200 KB

  char* w = (char*)d_ws;
  float* hsum    = (float*)(w);                    // N x 256
  float* feat    = (float*)(w + SZ_NH);            // N x 256
  float* hn      = (float*)(w + 2 * SZ_NH);        // N x 128
  char*  w2      = w + 2 * SZ_NH + SZ_NF;
  float* el      = (float*)(w2);
  float* er      = (float*)(w2 + SZ_N);
  float* dotl    = (float*)(w2 + 2 * SZ_N);
  float* dotr    = (float*)(w2 + 3 * SZ_N);
  int*   deg     = (int*)  (w2 + 4 * SZ_N);        // 3N ints
  int*   cursor  = (int*)  (w2 + 7 * SZ_N);        // 3N ints
  int*   row_ptr = (int*)  (w2 + 10 * SZ_N);       // 3N+1 ints (+pad)
  int*   csr_src = (int*)  (w2 + 14 * SZ_N);       // 3E ints

  const int B = 256;

  // ---------------- CSR build (shared by both layers) ---------------------
  hipMemsetAsync(deg, 0, 3 * SZ_N, stream);
  hipMemsetAsync(cursor, 0, 3 * SZ_N, stream);
  count_deg<<<(NREL * NE + B - 1) / B, B, 0, stream>>>(edges, deg);
  scan_deg<<<NREL, 1024, 0, stream>>>(deg, row_ptr);
  fill_csr<<<(NREL * NE + B - 1) / B, B, 0, stream>>>(edges, row_ptr, cursor, csr_src);

  const int AGG_G = (NN + 3) / 4;

  // ---------------- layer 1: x(128) -> h1(256), mean+relu -----------------
  for (int r = 0; r < NREL; ++r) {
    dim3 g1((NN + 63) / 64, HD / 64);
    gemm_f32<<<g1, B, 0, stream>>>(x, W1 + (size_t)r * FIN * HD, feat, NN, HD, FIN);
    rowdot2<<<(NN + 3) / 4, B, 0, stream>>>(feat, al1 + (size_t)r * HD,
                                            ar1 + (size_t)r * HD, el, er, NN, HD);
    gat_aggregate<HD><<<AGG_G, B, 0, stream>>>(
        row_ptr + r * NN, csr_src, el, er, feat,
        b1 + (size_t)r * HD, hsum, r == 0);
  }
  scale_relu<<<(NN * (HD / 4) + B - 1) / B, B, 0, stream>>>(
      hsum, 1.f / 3.f, 1, NN * (HD / 4));

  // ---------------- layer 2: h(256) -> h2(128), mean ----------------------
  for (int r = 0; r < NREL; ++r) {
    dim3 g2((NN + 63) / 64, FIN / 64);
    gemm_f32<<<g2, B, 0, stream>>>(hsum, W2 + (size_t)r * HD * FIN, feat, NN, FIN, HD);
    rowdot2<<<(NN + 3) / 4, B, 0, stream>>>(feat, al2 + (size_t)r * FIN,
                                            ar2 + (size_t)r * FIN, el, er, NN, FIN);
    gat_aggregate<FIN><<<AGG_G, B, 0, stream>>>(
        row_ptr + r * NN, csr_src, el, er, feat,
        b2 + (size_t)r * FIN, hn, r == 0);
  }
  scale_relu<<<(NN * (FIN / 4) + B - 1) / B, B, 0, stream>>>(
      hn, 1.f / 3.f, 0, NN * (FIN / 4));

  // ---------------- pair predictor ----------------------------------------
  node_dots<<<(NN + 3) / 4, B, 0, stream>>>(hn, Wlin, dotl, dotr, NN);
  const int TOT = NREL * NE + NP;
  pair_out<<<(TOT + B - 1) / B, B, 0, stream>>>(edges, npairs, dotl, dotr, blin, out);
}

// Round 4
// 597.526 us; speedup vs baseline: 7.5852x; 1.4031x over previous
//
#include <hip/hip_runtime.h>
#include <cstddef>

#define NN 50000
#define NREL 3
#define NE 250000
#define NP 100000
#define FIN 128
#define HD 256
#define SLOPE 0.2f

typedef short bf16x8 __attribute__((ext_vector_type(8)));
typedef float f32x4 __attribute__((ext_vector_type(4)));

__device__ __forceinline__ short f2bf(float f) {
  unsigned u = __float_as_uint(f);
  unsigned r = (u + 0x7FFFu + ((u >> 16) & 1u)) >> 16;   // RNE
  return (short)r;
}

// ---------------- bf16 MFMA GEMM: C[M,N] = A[M,K] @ Bt[N,K]^T -------------
// one wave computes a 64x64 tile; block = 4 waves stacked along M (256 rows).
__global__ __launch_bounds__(256) void gemm_mfma(
    const short* __restrict__ A,    // [M][K] bf16
    const short* __restrict__ Bt,   // [N][K] bf16 (B transposed)
    float* __restrict__ C,          // [M][N] f32
    int M, int N, int K)
{
  const int lane = threadIdx.x & 63;
  const int wave = threadIdx.x >> 6;
  const int m0 = blockIdx.x * 256 + wave * 64;
  const int n0 = blockIdx.y * 64;
  const int lrow = lane & 15;
  const int koff = (lane >> 4) * 8;

  f32x4 acc[4][4] = {};
  for (int k0 = 0; k0 < K; k0 += 32) {
    bf16x8 a[4], b[4];
#pragma unroll
    for (int i = 0; i < 4; ++i) {
      int row = m0 + i * 16 + lrow;
      row = row < M ? row : M - 1;
      a[i] = *(const bf16x8*)&A[(size_t)row * K + k0 + koff];
    }
#pragma unroll
    for (int j = 0; j < 4; ++j) {
      int col = n0 + j * 16 + lrow;
      b[j] = *(const bf16x8*)&Bt[(size_t)col * K + k0 + koff];
    }
#pragma unroll
    for (int i = 0; i < 4; ++i)
#pragma unroll
      for (int j = 0; j < 4; ++j)
        acc[i][j] = __builtin_amdgcn_mfma_f32_16x16x32_bf16(a[i], b[j], acc[i][j], 0, 0, 0);
  }
#pragma unroll
  for (int i = 0; i < 4; ++i) {
#pragma unroll
    for (int v = 0; v < 4; ++v) {
      int row = m0 + i * 16 + (lane >> 4) * 4 + v;
      if (row < M) {
#pragma unroll
        for (int j = 0; j < 4; ++j)
          C[(size_t)row * N + n0 + j * 16 + (lane & 15)] = acc[i][j][v];
      }
    }
  }
}

// ---------------- f32 -> bf16 (flat, n multiple of 4) ---------------------
__global__ __launch_bounds__(256) void conv_bf16(
    const float* __restrict__ in, short* __restrict__ out, int n)
{
  int i = (blockIdx.x * 256 + threadIdx.x) * 4;
  if (i >= n) return;
  float4 v = *(const float4*)&in[i];
  short4 o = {f2bf(v.x), f2bf(v.y), f2bf(v.z), f2bf(v.w)};
  *(short4*)&out[i] = o;
}

// ---------------- relu(x/3) -> bf16 ---------------------------------------
__global__ __launch_bounds__(256) void relu_scale_conv(
    const float* __restrict__ in, short* __restrict__ out, int n)
{
  int i = (blockIdx.x * 256 + threadIdx.x) * 4;
  if (i >= n) return;
  float4 v = *(const float4*)&in[i];
  const float s = 1.f / 3.f;
  short4 o = {f2bf(fmaxf(v.x * s, 0.f)), f2bf(fmaxf(v.y * s, 0.f)),
              f2bf(fmaxf(v.z * s, 0.f)), f2bf(fmaxf(v.w * s, 0.f))};
  *(short4*)&out[i] = o;
}

// ---------------- W[r][K][N] f32 -> Wt[r][N][K] bf16 ----------------------
__global__ __launch_bounds__(256) void wt_conv(
    const float* __restrict__ W, short* __restrict__ Wt, int R, int K, int N)
{
  int tid = blockIdx.x * 256 + threadIdx.x;
  if (tid >= R * K * N) return;
  int r = tid / (K * N);
  int rem = tid - r * K * N;
  int n = rem / K;
  int k = rem - n * K;
  Wt[tid] = f2bf(W[((size_t)r * K + k) * N + n]);
}

// ------------- per-row dual dot: el[i]=feat[i,:]·al, er[i]=feat[i,:]·ar ----
__global__ __launch_bounds__(256) void rowdot2(
    const float* __restrict__ feat, const float* __restrict__ al,
    const float* __restrict__ ar, float* __restrict__ el,
    float* __restrict__ er, int M, int H)
{
  const int wid  = (blockIdx.x * blockDim.x + threadIdx.x) >> 6;
  const int lane = threadIdx.x & 63;
  if (wid >= M) return;
  float sl = 0.f, sr = 0.f;
  for (int c = lane; c < H; c += 64) {
    float f = feat[(size_t)wid * H + c];
    sl += f * al[c];
    sr += f * ar[c];
  }
#pragma unroll
  for (int off = 32; off > 0; off >>= 1) {
    sl += __shfl_down(sl, off);
    sr += __shfl_down(sr, off);
  }
  if (lane == 0) { el[wid] = sl; er[wid] = sr; }
}

// ------------- CSR build: degree count ------------------------------------
__global__ __launch_bounds__(256) void count_deg(
    const int* __restrict__ edges, int* __restrict__ deg)
{
  int tid = blockIdx.x * blockDim.x + threadIdx.x;
  if (tid >= NREL * NE) return;
  int r = tid / NE;
  int e = tid - r * NE;
  int d = edges[(size_t)r * 2 * NE + NE + e];
  atomicAdd(&deg[r * NN + d], 1);
}

// ------------- CSR scan phase 1: per-block (1000 nodes) partial sums ------
__global__ __launch_bounds__(256) void deg_partial(
    const int* __restrict__ deg, int* __restrict__ psum)
{
  const int b = blockIdx.x;           // 0..149, flat over NREL*NN
  const int t = threadIdx.x;
  int4 v = {0, 0, 0, 0};
  if (t < 250) v = *(const int4*)&deg[b * 1000 + t * 4];
  int s = v.x + v.y + v.z + v.w;
#pragma unroll
  for (int off = 32; off > 0; off >>= 1) s += __shfl_down(s, off);
  __shared__ int ws[4];
  if ((t & 63) == 0) ws[t >> 6] = s;
  __syncthreads();
  if (t == 0) psum[b] = ws[0] + ws[1] + ws[2] + ws[3];
}

// ------------- CSR scan phase 2: scan the 150 partials (1 block) ----------
// global exclusive scan == per-relation scan + r*NE (each relation has NE edges)
__global__ __launch_bounds__(256) void scan_psum(
    const int* __restrict__ psum, int* __restrict__ pexcl)
{
  __shared__ int lds[256];
  const int t = threadIdx.x;
  int v = (t < 150) ? psum[t] : 0;
  lds[t] = v;
  __syncthreads();
  for (int off = 1; off < 256; off <<= 1) {
    int add = (t >= off) ? lds[t - off] : 0;
    __syncthreads();
    lds[t] += add;
    __syncthreads();
  }
  if (t < 150) pexcl[t] = lds[t] - v;
}

// ------------- CSR scan phase 3: local scan + write row_ptr ---------------
__global__ __launch_bounds__(256) void deg_rowptr(
    const int* __restrict__ deg, const int* __restrict__ pexcl,
    int* __restrict__ row_ptr)
{
  const int b = blockIdx.x;
  const int t = threadIdx.x;
  int4 v = {0, 0, 0, 0};
  if (t < 250) v = *(const int4*)&deg[b * 1000 + t * 4];
  int s = v.x + v.y + v.z + v.w;
  __shared__ int lds[256];
  lds[t] = s;
  __syncthreads();
  for (int off = 1; off < 256; off <<= 1) {
    int add = (t >= off) ? lds[t - off] : 0;
    __syncthreads();
    lds[t] += add;
    __syncthreads();
  }
  int run = lds[t] - s + pexcl[b];
  if (t < 250) {
    int i = b * 1000 + t * 4;
    row_ptr[i] = run;     run += v.x;
    row_ptr[i + 1] = run; run += v.y;
    row_ptr[i + 2] = run; run += v.z;
    row_ptr[i + 3] = run;
  }
  if (b == 0 && t == 0) row_ptr[NREL * NN] = NREL * NE;
}

// ------------- CSR build: fill src lists ----------------------------------
__global__ __launch_bounds__(256) void fill_csr(
    const int* __restrict__ edges, const int* __restrict__ row_ptr,
    int* __restrict__ cursor, int* __restrict__ csr_src)
{
  int tid = blockIdx.x * blockDim.x + threadIdx.x;
  if (tid >= NREL * NE) return;
  int r = tid / NE;
  int e = tid - r * NE;
  const int* base = edges + (size_t)r * 2 * NE;
  int s = base[e];
  int d = base[NE + e];
  int pos = atomicAdd(&cursor[r * NN + d], 1);
  csr_src[row_ptr[r * NN + d] + pos] = s;
}

// ------------- fused GAT aggregate: one wave per dst node -----------------
template<int H>
__global__ __launch_bounds__(256) void gat_aggregate(
    const int* __restrict__ row_ptr, const int* __restrict__ csr_src,
    const float* __restrict__ el, const float* __restrict__ er,
    const float* __restrict__ feat, const float* __restrict__ bias,
    float* __restrict__ acc, int first)
{
  constexpr int V = H / 64;
  typedef float vec_t __attribute__((ext_vector_type(V)));
  const int lane = threadIdx.x & 63;
  const int node = blockIdx.x * 4 + (threadIdx.x >> 6);
  if (node >= NN) return;
  const int beg = row_ptr[node];
  const int end = row_ptr[node + 1];
  const float eri = er[node];

  float m = -3.4e38f;
  for (int e = beg + lane; e < end; e += 64) {
    float s = el[csr_src[e]] + eri;
    s = s > 0.f ? s : SLOPE * s;
    m = fmaxf(m, s);
  }
#pragma unroll
  for (int off = 32; off > 0; off >>= 1) m = fmaxf(m, __shfl_xor(m, off));

  float denom = 0.f;
  vec_t facc = (vec_t)0.f;
  for (int chunk = beg; chunk < end; chunk += 64) {
    int e = chunk + lane;
    float a = 0.f;
    int sidx = 0;
    if (e < end) {
      sidx = csr_src[e];
      float s = el[sidx] + eri;
      s = s > 0.f ? s : SLOPE * s;
      a = __expf(s - m);
    }
    const int cnt = (end - chunk < 64) ? end - chunk : 64;
    for (int j = 0; j < cnt; ++j) {
      float aj = __shfl(a, j);
      int   sj = __shfl(sidx, j);
      denom += aj;
      const vec_t f = *(const vec_t*)&feat[(size_t)sj * H + lane * V];
      facc += f * aj;
    }
  }
  const float inv = 1.f / fmaxf(denom, 1e-9f);
  const vec_t bv = *(const vec_t*)&bias[lane * V];
  vec_t res = facc * inv + bv;
  float* dst = &acc[(size_t)node * H + lane * V];
  if (!first) res += *(const vec_t*)dst;
  *(vec_t*)dst = res;
}

// ------------- p *= s (in place, float4, no relu) -------------------------
__global__ __launch_bounds__(256) void scale_only(
    float* __restrict__ p, float s, int n4)
{
  int idx = blockIdx.x * blockDim.x + threadIdx.x;
  if (idx >= n4) return;
  float4 v = ((float4*)p)[idx];
  v.x *= s; v.y *= s; v.z *= s; v.w *= s;
  ((float4*)p)[idx] = v;
}

// ------------- per-node predictor dots: dotl/dotr (H=128) -----------------
__global__ __launch_bounds__(256) void node_dots(
    const float* __restrict__ hn, const float* __restrict__ Wlin,
    float* __restrict__ dotl, float* __restrict__ dotr, int M)
{
  const int wid  = (blockIdx.x * blockDim.x + threadIdx.x) >> 6;
  const int lane = threadIdx.x & 63;
  if (wid >= M) return;
  float f1 = fmaxf(hn[(size_t)wid * FIN + lane], 0.f);
  float f2 = fmaxf(hn[(size_t)wid * FIN + lane + 64], 0.f);
  float dl = f1 * Wlin[lane] + f2 * Wlin[lane + 64];
  float dr = f1 * Wlin[FIN + lane] + f2 * Wlin[FIN + lane + 64];
#pragma unroll
  for (int off = 32; off > 0; off >>= 1) {
    dl += __shfl_down(dl, off);
    dr += __shfl_down(dr, off);
  }
  if (lane == 0) { dotl[wid] = dl; dotr[wid] = dr; }
}

// ------------- pair logits -------------------------------------------------
__global__ __launch_bounds__(256) void pair_out(
    const int* __restrict__ edges, const int* __restrict__ n_pairs,
    const float* __restrict__ dotl, const float* __restrict__ dotr,
    const float* __restrict__ blin, float* __restrict__ out)
{
  const int TOT = NREL * NE + NP;
  int p = blockIdx.x * blockDim.x + threadIdx.x;
  if (p >= TOT) return;
  int s, d;
  if (p < NREL * NE) {
    int r = p / NE;
    int e = p - r * NE;
    const int* base = edges + (size_t)r * 2 * NE;
    s = base[e];
    d = base[NE + e];
  } else {
    int q = p - NREL * NE;
    s = n_pairs[2 * q];
    d = n_pairs[2 * q + 1];
  }
  float logit = dotl[s] + dotr[d] + blin[0];
  out[p] = 1.f / (1.f + expf(-logit));
}

extern "C" void kernel_launch(void* const* d_in, const int* in_sizes, int n_in,
                              void* d_out, int out_size, void* d_ws, size_t ws_size,
                              hipStream_t stream) {
  const float* x      = (const float*)d_in[0];
  const int*   edges  = (const int*)d_in[1];
  const int*   npairs = (const int*)d_in[2];
  const float* W1     = (const float*)d_in[3];
  const float* al1    = (const float*)d_in[4];
  const float* ar1    = (const float*)d_in[5];
  const float* b1     = (const float*)d_in[6];
  const float* W2     = (const float*)d_in[7];
  const float* al2    = (const float*)d_in[8];
  const float* ar2    = (const float*)d_in[9];
  const float* b2     = (const float*)d_in[10];
  const float* Wlin   = (const float*)d_in[11];
  const float* blin   = (const float*)d_in[12];
  float* out = (float*)d_out;

  const size_t SZ_NH  = (size_t)NN * HD * sizeof(float);    // 51.2 MB
  const size_t SZ_NF  = (size_t)NN * FIN * sizeof(float);   // 25.6 MB
  const size_t SZ_N   = (size_t)NN * sizeof(float);         // 200 KB
  const size_t SZ_XB  = (size_t)NN * FIN * sizeof(short);   // 12.8 MB
  const size_t SZ_HB  = (size_t)NN * HD * sizeof(short);    // 25.6 MB
  const size_t SZ_WT  = (size_t)NREL * FIN * HD * sizeof(short); // 196.6 KB

  char* w = (char*)d_ws;
  float* hsum    = (float*)(w);                    // N x 256 f32
  float* feat    = (float*)(w + SZ_NH);            // N x 256 f32
  float* hn      = (float*)(w + 2 * SZ_NH);        // N x 128 f32
  short* xb      = (short*)(w + 2 * SZ_NH + SZ_NF);
  short* hb      = (short*)(w + 2 * SZ_NH + SZ_NF + SZ_XB);
  short* W1t     = (short*)(w + 2 * SZ_NH + SZ_NF + SZ_XB + SZ_HB);
  short* W2t     = (short*)((char*)W1t + SZ_WT);
  char*  w2      = (char*)W2t + SZ_WT;
  float* el      = (float*)(w2);
  float* er      = (float*)(w2 + SZ_N);
  float* dotl    = (float*)(w2 + 2 * SZ_N);
  float* dotr    = (float*)(w2 + 3 * SZ_N);
  int*   deg     = (int*)  (w2 + 4 * SZ_N);        // 3N ints
  int*   cursor  = (int*)  (w2 + 7 * SZ_N);        // 3N ints
  int*   row_ptr = (int*)  (w2 + 10 * SZ_N);       // 3N+1 ints (+pad)
  int*   psum    = (int*)  (w2 + 14 * SZ_N);       // 150 ints
  int*   pexcl   = (int*)  (w2 + 14 * SZ_N + 1024);
  int*   csr_src = (int*)  (w2 + 14 * SZ_N + 4096);// 3E ints

  const int B = 256;

  // ---------------- input conversions -------------------------------------
  conv_bf16<<<(NN * FIN / 4 + B - 1) / B, B, 0, stream>>>(x, xb, NN * FIN);
  wt_conv<<<(NREL * FIN * HD + B - 1) / B, B, 0, stream>>>(W1, W1t, NREL, FIN, HD);
  wt_conv<<<(NREL * HD * FIN + B - 1) / B, B, 0, stream>>>(W2, W2t, NREL, HD, FIN);

  // ---------------- CSR build (shared by both layers) ---------------------
  hipMemsetAsync(deg, 0, 3 * SZ_N, stream);
  hipMemsetAsync(cursor, 0, 3 * SZ_N, stream);
  count_deg<<<(NREL * NE + B - 1) / B, B, 0, stream>>>(edges, deg);
  deg_partial<<<150, B, 0, stream>>>(deg, psum);
  scan_psum<<<1, B, 0, stream>>>(psum, pexcl);
  deg_rowptr<<<150, B, 0, stream>>>(deg, pexcl, row_ptr);
  fill_csr<<<(NREL * NE + B - 1) / B, B, 0, stream>>>(edges, row_ptr, cursor, csr_src);

  const int AGG_G = (NN + 3) / 4;
  const int GX = (NN + 255) / 256;

  // ---------------- layer 1: x(128) -> h1(256), mean+relu -----------------
  for (int r = 0; r < NREL; ++r) {
    dim3 g1(GX, HD / 64);
    gemm_mfma<<<g1, B, 0, stream>>>(xb, W1t + (size_t)r * HD * FIN, feat, NN, HD, FIN);
    rowdot2<<<(NN + 3) / 4, B, 0, stream>>>(feat, al1 + (size_t)r * HD,
                                            ar1 + (size_t)r * HD, el, er, NN, HD);
    gat_aggregate<HD><<<AGG_G, B, 0, stream>>>(
        row_ptr + r * NN, csr_src, el, er, feat,
        b1 + (size_t)r * HD, hsum, r == 0);
  }
  relu_scale_conv<<<(NN * HD / 4 + B - 1) / B, B, 0, stream>>>(hsum, hb, NN * HD);

  // ---------------- layer 2: h(256) -> h2(128), mean ----------------------
  for (int r = 0; r < NREL; ++r) {
    dim3 g2(GX, FIN / 64);
    gemm_mfma<<<g2, B, 0, stream>>>(hb, W2t + (size_t)r * FIN * HD, feat, NN, FIN, HD);
    rowdot2<<<(NN + 3) / 4, B, 0, stream>>>(feat, al2 + (size_t)r * FIN,
                                            ar2 + (size_t)r * FIN, el, er, NN, FIN);
    gat_aggregate<FIN><<<AGG_G, B, 0, stream>>>(
        row_ptr + r * NN, csr_src, el, er, feat,
        b2 + (size_t)r * FIN, hn, r == 0);
  }
  scale_only<<<(NN * (FIN / 4) + B - 1) / B, B, 0, stream>>>(
      hn, 1.f / 3.f, NN * (FIN / 4));

  // ---------------- pair predictor ----------------------------------------
  node_dots<<<(NN + 3) / 4, B, 0, stream>>>(hn, Wlin, dotl, dotr, NN);
  const int TOT = NREL * NE + NP;
  pair_out<<<(TOT + B - 1) / B, B, 0, stream>>>(edges, npairs, dotl, dotr, blin, out);
}

// Round 5
// 387.479 us; speedup vs baseline: 11.6970x; 1.5421x over previous
//
#include <hip/hip_runtime.h>
#include <cstddef>

#define NN 50000
#define NREL 3
#define NE 250000
#define NP 100000
#define FIN 128
#define HD 256
#define SLOPE 0.2f

typedef short bf16x8 __attribute__((ext_vector_type(8)));
typedef float f32x4 __attribute__((ext_vector_type(4)));

__device__ __forceinline__ short f2bf(float f) {
  unsigned u = __float_as_uint(f);
  unsigned r = (u + 0x7FFFu + ((u >> 16) & 1u)) >> 16;   // RNE
  return (short)r;
}
__device__ __forceinline__ float bf2f(short s) {
  return __uint_as_float(((unsigned)(unsigned short)s) << 16);
}

// ---- fused bf16 MFMA GEMM + el/er epilogue, batched over relations -------
// C = A[M,K] @ Wt[r][N_][K]^T ; writes featb[r] (bf16) and el/er[r] (f32).
// Block covers WM*64 rows x WN*64 = N_ cols (full row width).
template<int N_, int WM, int WN>
__global__ __launch_bounds__(256) void gemm_fused(
    const short* __restrict__ A,     // [M][K] bf16
    const short* __restrict__ Wt,    // [NREL][N_][K] bf16
    const float* __restrict__ al,    // [NREL][N_]
    const float* __restrict__ ar,    // [NREL][N_]
    short* __restrict__ featb,       // [NREL][M][N_] bf16
    float* __restrict__ el,          // [NREL][NN]
    float* __restrict__ er,          // [NREL][NN]
    int M, int K)
{
  const int r = blockIdx.y;
  const short* Bt  = Wt + (size_t)r * N_ * K;
  const float* alr = al + r * N_;
  const float* arr = ar + r * N_;
  short* fb  = featb + (size_t)r * M * N_;
  float* elr = el + r * NN;
  float* err = er + r * NN;

  const int lane = threadIdx.x & 63;
  const int wave = threadIdx.x >> 6;
  const int wm = wave / WN;
  const int wn = wave % WN;
  const int m0 = blockIdx.x * (WM * 64) + wm * 64;
  const int n0 = wn * 64;
  const int c    = lane & 15;
  const int rgrp = lane >> 4;
  const int koff = rgrp * 8;

  f32x4 acc[4][4] = {};
  for (int k0 = 0; k0 < K; k0 += 32) {
    bf16x8 a[4], b[4];
#pragma unroll
    for (int i = 0; i < 4; ++i) {
      int row = m0 + i * 16 + c;
      row = row < M ? row : M - 1;
      a[i] = *(const bf16x8*)&A[(size_t)row * K + k0 + koff];
    }
#pragma unroll
    for (int j = 0; j < 4; ++j)
      b[j] = *(const bf16x8*)&Bt[(size_t)(n0 + j * 16 + c) * K + k0 + koff];
#pragma unroll
    for (int i = 0; i < 4; ++i)
#pragma unroll
      for (int j = 0; j < 4; ++j)
        acc[i][j] = __builtin_amdgcn_mfma_f32_16x16x32_bf16(a[i], b[j], acc[i][j], 0, 0, 0);
  }

  // ---- epilogue: featb (bf16) + el/er partial dots from f32 acc ----------
  __shared__ float2 part[WN][WM * 64];
  float pe[4][4], pr[4][4];                     // [i][v]
#pragma unroll
  for (int i = 0; i < 4; ++i)
#pragma unroll
    for (int v = 0; v < 4; ++v) {
      float se = 0.f, sr = 0.f;
#pragma unroll
      for (int j = 0; j < 4; ++j) {
        float av = acc[i][j][v];
        int col = n0 + j * 16 + c;
        se = fmaf(av, alr[col], se);
        sr = fmaf(av, arr[col], sr);
      }
      pe[i][v] = se; pr[i][v] = sr;
    }
#pragma unroll
  for (int i = 0; i < 4; ++i) {
#pragma unroll
    for (int v = 0; v < 4; ++v) {
      int row = m0 + i * 16 + rgrp * 4 + v;
      if (row < M) {
#pragma unroll
        for (int j = 0; j < 4; ++j)
          fb[(size_t)row * N_ + n0 + j * 16 + c] = f2bf(acc[i][j][v]);
      }
#pragma unroll
      for (int off = 1; off < 16; off <<= 1) {
        pe[i][v] += __shfl_xor(pe[i][v], off);
        pr[i][v] += __shfl_xor(pr[i][v], off);
      }
    }
  }
  if (c == 0) {
#pragma unroll
    for (int i = 0; i < 4; ++i)
#pragma unroll
      for (int v = 0; v < 4; ++v)
        part[wn][wm * 64 + i * 16 + rgrp * 4 + v] = make_float2(pe[i][v], pr[i][v]);
  }
  __syncthreads();
  const int t = threadIdx.x;
  if (t < WM * 64) {
    float se = 0.f, sr = 0.f;
#pragma unroll
    for (int w = 0; w < WN; ++w) { se += part[w][t].x; sr += part[w][t].y; }
    int row = blockIdx.x * (WM * 64) + t;
    if (row < M) { elr[row] = se; err[row] = sr; }
  }
}

// ---------------- f32 -> bf16 (flat, n multiple of 4) ---------------------
__global__ __launch_bounds__(256) void conv_bf16(
    const float* __restrict__ in, short* __restrict__ out, int n)
{
  int i = (blockIdx.x * 256 + threadIdx.x) * 4;
  if (i >= n) return;
  float4 v = *(const float4*)&in[i];
  short4 o = {f2bf(v.x), f2bf(v.y), f2bf(v.z), f2bf(v.w)};
  *(short4*)&out[i] = o;
}

// ---------------- W[r][K][N] f32 -> Wt[r][N][K] bf16 ----------------------
__global__ __launch_bounds__(256) void wt_conv(
    const float* __restrict__ W, short* __restrict__ Wt, int R, int K, int N)
{
  int tid = blockIdx.x * 256 + threadIdx.x;
  if (tid >= R * K * N) return;
  int r = tid / (K * N);
  int rem = tid - r * K * N;
  int n = rem / K;
  int k = rem - n * K;
  Wt[tid] = f2bf(W[((size_t)r * K + k) * N + n]);
}

// ------------- CSR build: degree count ------------------------------------
__global__ __launch_bounds__(256) void count_deg(
    const int* __restrict__ edges, int* __restrict__ deg)
{
  int tid = blockIdx.x * blockDim.x + threadIdx.x;
  if (tid >= NREL * NE) return;
  int r = tid / NE;
  int e = tid - r * NE;
  int d = edges[(size_t)r * 2 * NE + NE + e];
  atomicAdd(&deg[r * NN + d], 1);
}

// ------------- CSR scan phase 1: per-block (1000 nodes) partial sums ------
__global__ __launch_bounds__(256) void deg_partial(
    const int* __restrict__ deg, int* __restrict__ psum)
{
  const int b = blockIdx.x;           // 0..149 flat over NREL*NN
  const int t = threadIdx.x;
  int4 v = {0, 0, 0, 0};
  if (t < 250) v = *(const int4*)&deg[b * 1000 + t * 4];
  int s = v.x + v.y + v.z + v.w;
#pragma unroll
  for (int off = 32; off > 0; off >>= 1) s += __shfl_down(s, off);
  __shared__ int ws[4];
  if ((t & 63) == 0) ws[t >> 6] = s;
  __syncthreads();
  if (t == 0) psum[b] = ws[0] + ws[1] + ws[2] + ws[3];
}

// ------------- CSR scan phase 2: scan the 150 partials (1 block) ----------
__global__ __launch_bounds__(256) void scan_psum(
    const int* __restrict__ psum, int* __restrict__ pexcl)
{
  __shared__ int lds[256];
  const int t = threadIdx.x;
  int v = (t < 150) ? psum[t] : 0;
  lds[t] = v;
  __syncthreads();
  for (int off = 1; off < 256; off <<= 1) {
    int add = (t >= off) ? lds[t - off] : 0;
    __syncthreads();
    lds[t] += add;
    __syncthreads();
  }
  if (t < 150) pexcl[t] = lds[t] - v;
}

// ------------- CSR scan phase 3: local scan + write row_ptr ---------------
__global__ __launch_bounds__(256) void deg_rowptr(
    const int* __restrict__ deg, const int* __restrict__ pexcl,
    int* __restrict__ row_ptr)
{
  const int b = blockIdx.x;
  const int t = threadIdx.x;
  int4 v = {0, 0, 0, 0};
  if (t < 250) v = *(const int4*)&deg[b * 1000 + t * 4];
  int s = v.x + v.y + v.z + v.w;
  __shared__ int lds[256];
  lds[t] = s;
  __syncthreads();
  for (int off = 1; off < 256; off <<= 1) {
    int add = (t >= off) ? lds[t - off] : 0;
    __syncthreads();
    lds[t] += add;
    __syncthreads();
  }
  int run = lds[t] - s + pexcl[b];
  if (t < 250) {
    int i = b * 1000 + t * 4;
    row_ptr[i] = run;     run += v.x;
    row_ptr[i + 1] = run; run += v.y;
    row_ptr[i + 2] = run; run += v.z;
    row_ptr[i + 3] = run;
  }
  if (b == 0 && t == 0) row_ptr[NREL * NN] = NREL * NE;
}

// ------------- CSR build: fill src lists ----------------------------------
__global__ __launch_bounds__(256) void fill_csr(
    const int* __restrict__ edges, const int* __restrict__ row_ptr,
    int* __restrict__ cursor, int* __restrict__ csr_src)
{
  int tid = blockIdx.x * blockDim.x + threadIdx.x;
  if (tid >= NREL * NE) return;
  int r = tid / NE;
  int e = tid - r * NE;
  const int* base = edges + (size_t)r * 2 * NE;
  int s = base[e];
  int d = base[NE + e];
  int pos = atomicAdd(&cursor[r * NN + d], 1);
  csr_src[row_ptr[r * NN + d] + pos] = s;
}

// ------------- fused 3-relation GAT aggregate, one wave per dst node ------
// L1: out = relu(sum_r(...)/3) -> hb (bf16).  !L1: fused predictor dots.
template<int H, int L1>
__global__ __launch_bounds__(256) void gat_aggregate3(
    const int* __restrict__ row_ptr,   // [NREL*NN+1], absolute indices
    const int* __restrict__ csr_src,
    const float* __restrict__ el,      // [NREL][NN]
    const float* __restrict__ er,      // [NREL][NN]
    const short* __restrict__ featb,   // [NREL][NN][H] bf16
    const float* __restrict__ bias,    // [NREL][H]
    short* __restrict__ hb,            // L1 out [NN][H] bf16
    const float* __restrict__ Wlin,    // !L1
    float* __restrict__ dotl, float* __restrict__ dotr)
{
  constexpr int V = H / 64;
  typedef float vec_t  __attribute__((ext_vector_type(V)));
  typedef short svec_t __attribute__((ext_vector_type(V)));
  const int lane = threadIdx.x & 63;
  const int node = blockIdx.x * 4 + (threadIdx.x >> 6);
  if (node >= NN) return;

  vec_t tot = (vec_t)0.f;
#pragma unroll
  for (int r = 0; r < NREL; ++r) {
    const int beg = row_ptr[r * NN + node];
    const int end = row_ptr[r * NN + node + 1];
    const float eri = er[r * NN + node];
    const float* elr = el + r * NN;
    const short* fb  = featb + (size_t)r * NN * H;

    float m = -3.4e38f;
    for (int e = beg + lane; e < end; e += 64) {
      float s = elr[csr_src[e]] + eri;
      s = s > 0.f ? s : SLOPE * s;
      m = fmaxf(m, s);
    }
#pragma unroll
    for (int off = 32; off > 0; off >>= 1) m = fmaxf(m, __shfl_xor(m, off));

    float denom = 0.f;
    vec_t facc = (vec_t)0.f;
    for (int chunk = beg; chunk < end; chunk += 64) {
      int e = chunk + lane;
      float a = 0.f;
      int sidx = 0;
      if (e < end) {
        sidx = csr_src[e];
        float s = elr[sidx] + eri;
        s = s > 0.f ? s : SLOPE * s;
        a = __expf(s - m);
      }
      const int cnt = (end - chunk < 64) ? end - chunk : 64;
      for (int j = 0; j < cnt; ++j) {
        float aj = __shfl(a, j);
        int   sj = __shfl(sidx, j);
        denom += aj;
        const svec_t f16 = *(const svec_t*)&fb[(size_t)sj * H + lane * V];
        vec_t f;
#pragma unroll
        for (int k = 0; k < V; ++k) f[k] = bf2f(f16[k]);
        facc += f * aj;
      }
    }
    const float inv = 1.f / fmaxf(denom, 1e-9f);
    const float* br = bias + r * H;
    vec_t bv;
#pragma unroll
    for (int k = 0; k < V; ++k) bv[k] = br[lane * V + k];
    tot += facc * inv + bv;
  }

  if (L1) {
    svec_t o;
#pragma unroll
    for (int k = 0; k < V; ++k) o[k] = f2bf(fmaxf(tot[k] * (1.f / 3.f), 0.f));
    *(svec_t*)&hb[(size_t)node * H + lane * V] = o;
  } else {
    float dl = 0.f, dr = 0.f;
#pragma unroll
    for (int k = 0; k < V; ++k) {
      int c = lane * V + k;
      float f = fmaxf(tot[k] * (1.f / 3.f), 0.f);
      dl = fmaf(f, Wlin[c], dl);
      dr = fmaf(f, Wlin[FIN + c], dr);
    }
#pragma unroll
    for (int off = 32; off > 0; off >>= 1) {
      dl += __shfl_xor(dl, off);
      dr += __shfl_xor(dr, off);
    }
    if (lane == 0) { dotl[node] = dl; dotr[node] = dr; }
  }
}

// ------------- pair logits -------------------------------------------------
__global__ __launch_bounds__(256) void pair_out(
    const int* __restrict__ edges, const int* __restrict__ n_pairs,
    const float* __restrict__ dotl, const float* __restrict__ dotr,
    const float* __restrict__ blin, float* __restrict__ out)
{
  const int TOT = NREL * NE + NP;
  int p = blockIdx.x * blockDim.x + threadIdx.x;
  if (p >= TOT) return;
  int s, d;
  if (p < NREL * NE) {
    int r = p / NE;
    int e = p - r * NE;
    const int* base = edges + (size_t)r * 2 * NE;
    s = base[e];
    d = base[NE + e];
  } else {
    int q = p - NREL * NE;
    s = n_pairs[2 * q];
    d = n_pairs[2 * q + 1];
  }
  float logit = dotl[s] + dotr[d] + blin[0];
  out[p] = 1.f / (1.f + expf(-logit));
}

extern "C" void kernel_launch(void* const* d_in, const int* in_sizes, int n_in,
                              void* d_out, int out_size, void* d_ws, size_t ws_size,
                              hipStream_t stream) {
  const float* x      = (const float*)d_in[0];
  const int*   edges  = (const int*)d_in[1];
  const int*   npairs = (const int*)d_in[2];
  const float* W1     = (const float*)d_in[3];
  const float* al1    = (const float*)d_in[4];
  const float* ar1    = (const float*)d_in[5];
  const float* b1     = (const float*)d_in[6];
  const float* W2     = (const float*)d_in[7];
  const float* al2    = (const float*)d_in[8];
  const float* ar2    = (const float*)d_in[9];
  const float* b2     = (const float*)d_in[10];
  const float* Wlin   = (const float*)d_in[11];
  const float* blin   = (const float*)d_in[12];
  float* out = (float*)d_out;

  char* w = (char*)d_ws;
  size_t off = 0;
  short* xb      = (short*)(w + off); off += (size_t)NN * FIN * 2;        // 12.8 MB
  short* hb      = (short*)(w + off); off += (size_t)NN * HD * 2;         // 25.6 MB
  short* W1t     = (short*)(w + off); off += (size_t)NREL * FIN * HD * 2; // 196.6 KB
  short* W2t     = (short*)(w + off); off += (size_t)NREL * FIN * HD * 2;
  short* featb   = (short*)(w + off); off += (size_t)NREL * NN * HD * 2;  // 76.8 MB (reused L2)
  float* el      = (float*)(w + off); off += (size_t)NREL * NN * 4;
  float* er      = (float*)(w + off); off += (size_t)NREL * NN * 4;
  float* dotl    = (float*)(w + off); off += (size_t)NN * 4;
  float* dotr    = (float*)(w + off); off += (size_t)NN * 4;
  int*   deg     = (int*)  (w + off); off += (size_t)NREL * NN * 4;
  int*   cursor  = (int*)  (w + off); off += (size_t)NREL * NN * 4;
  int*   row_ptr = (int*)  (w + off); off += (size_t)(NREL * NN + 16) * 4;
  int*   psum    = (int*)  (w + off); off += 1024;
  int*   pexcl   = (int*)  (w + off); off += 1024;
  int*   csr_src = (int*)  (w + off); off += (size_t)NREL * NE * 4;

  const int B = 256;

  // ---------------- input conversions -------------------------------------
  conv_bf16<<<(NN * FIN / 4 + B - 1) / B, B, 0, stream>>>(x, xb, NN * FIN);
  wt_conv<<<(NREL * FIN * HD + B - 1) / B, B, 0, stream>>>(W1, W1t, NREL, FIN, HD);
  wt_conv<<<(NREL * HD * FIN + B - 1) / B, B, 0, stream>>>(W2, W2t, NREL, HD, FIN);

  // ---------------- CSR build (shared by both layers) ---------------------
  hipMemsetAsync(deg, 0, (size_t)NREL * NN * 4, stream);
  hipMemsetAsync(cursor, 0, (size_t)NREL * NN * 4, stream);
  count_deg<<<(NREL * NE + B - 1) / B, B, 0, stream>>>(edges, deg);
  deg_partial<<<150, B, 0, stream>>>(deg, psum);
  scan_psum<<<1, B, 0, stream>>>(psum, pexcl);
  deg_rowptr<<<150, B, 0, stream>>>(deg, pexcl, row_ptr);
  fill_csr<<<(NREL * NE + B - 1) / B, B, 0, stream>>>(edges, row_ptr, cursor, csr_src);

  const int AGG_G = (NN + 3) / 4;

  // ---------------- layer 1: x(128) -> h(256) bf16 ------------------------
  {
    dim3 g((NN + 63) / 64, NREL);
    gemm_fused<HD, 1, 4><<<g, B, 0, stream>>>(xb, W1t, al1, ar1, featb, el, er, NN, FIN);
    gat_aggregate3<HD, 1><<<AGG_G, B, 0, stream>>>(
        row_ptr, csr_src, el, er, featb, b1, hb, nullptr, nullptr, nullptr);
  }

  // ---------------- layer 2: h(256) -> dots(128) --------------------------
  {
    dim3 g((NN + 127) / 128, NREL);
    gemm_fused<FIN, 2, 2><<<g, B, 0, stream>>>(hb, W2t, al2, ar2, featb, el, er, NN, HD);
    gat_aggregate3<FIN, 0><<<AGG_G, B, 0, stream>>>(
        row_ptr, csr_src, el, er, featb, b2, nullptr, Wlin, dotl, dotr);
  }

  // ---------------- pair predictor ----------------------------------------
  const int TOT = NREL * NE + NP;
  pair_out<<<(TOT + B - 1) / B, B, 0, stream>>>(edges, npairs, dotl, dotr, blin, out);
}